// Round 5
// baseline (215.072 us; speedup 1.0000x reference)
//
#include <hip/hip_runtime.h>

// VectorQuantizer on MI355X — round 11: loss-from-distances algebra.
// (z_q - z)^2 summed = sum|z|^2 + sum(dist of chosen code), so the epilogue
// no longer reads z at all (pure gather-write + histogram, write-bound).
// Scan kernel (unchanged structure from r10, 48us) additionally accumulates
// sum|z|^2 exactly during staging; merge accumulates approx m1; rescue
// patches flagged tokens with (exact - approx). Rescue widened to 8
// tokens/block (codebook L2 traffic per token halved).
// z: [32,256,32,32] fp32; codebook: [1024,256] fp32; N=32768, K=1024, C=256.
// dist = |e|^2 - 2 z.e (|z|^2 argmin-invariant). Single-pass fp16 MFMA approx;
// tokens with approx top-2 gap <= DELTA=0.3 get an exact fp32 rescan.
//
// ws layout (bytes):
//   eh      @ 0        _Float16[1024*256]  (524288)
//   enorm   @ 524288   float[1024]
//   idx     @ 528384   int[32768]
//   counts  @ 659456   int[1024]
//   lsum    @ 663552   float
//   nflag   @ 663616   int
//   flag    @ 663680   int[32768]
// d_out scratch (epilogue rewrites all of out):
//   pm1 @ float[0..65536)   per-half best dist  [h][n]; after merge: [n]=merged
//   pm2 @ float[65536..)    per-half 2nd dist   [h][n]
//   pi  @ int  [131072..)   per-half best index [h][n]

#define BETA  0.25f
#define DELTA 0.3f

typedef _Float16 half8 __attribute__((ext_vector_type(8)));
typedef float    f32x4 __attribute__((ext_vector_type(4)));

// ---------------------------------------------------------------------------
// Kernel 1: codebook -> eh f16 + exact |e|^2 + init accumulators. grid 256.
// ---------------------------------------------------------------------------
__global__ __launch_bounds__(256) void vq_prep_cb(
    const float* __restrict__ cb, _Float16* __restrict__ eh,
    float* __restrict__ enorm, int* __restrict__ counts,
    float* __restrict__ lsum, int* __restrict__ nflag)
{
    const int tid = threadIdx.x;
    if (blockIdx.x < 4) counts[blockIdx.x * 256 + tid] = 0;
    if (blockIdx.x == 4 && tid == 0) { *lsum = 0.0f; *nflag = 0; }

    const int lane = tid & 63;
    const int r    = blockIdx.x * 4 + (tid >> 6);
    const float4 v = *reinterpret_cast<const float4*>(cb + r * 256 + lane * 4);
    _Float16 h0 = (_Float16)v.x, h1 = (_Float16)v.y, h2 = (_Float16)v.z, h3 = (_Float16)v.w;
    *reinterpret_cast<ushort4*>(eh + r * 256 + lane * 4) =
        make_ushort4(*(unsigned short*)&h0, *(unsigned short*)&h1,
                     *(unsigned short*)&h2, *(unsigned short*)&h3);
    float s = v.x * v.x + v.y * v.y + v.z * v.z + v.w * v.w;
    #pragma unroll
    for (int off = 32; off > 0; off >>= 1) s += __shfl_down(s, off);
    if (lane == 0) enorm[r] = s;
}

// ---------------------------------------------------------------------------
// Kernel 2: fused MFMA distance scan, code-split (r10 structure, 48us).
// grid 1024 x 256 threads: blockIdx = token-tile*2 + half. 64 tokens staged
// fp32->f16 into the xor-swizzled LDS tile; h==0 blocks also accumulate the
// exact fp32 sum|z|^2 into lsum (one atomic per wave).
// Wave w scans codes [h*512 + w*128, +128) in 4 tiles of 32 (mt=2, nt=4).
// Output: per-half top-2 partials (pm1/pm2/pi), merged by vq_merge.
// ---------------------------------------------------------------------------
__global__ __launch_bounds__(256) void vq_mfma(
    const float* __restrict__ z, const _Float16* __restrict__ eh,
    const float* __restrict__ enorm,
    float* __restrict__ pm1, float* __restrict__ pm2, int* __restrict__ pi,
    float* __restrict__ lsum)
{
    __shared__ _Float16 sB[64 * 256];
    __shared__ float smv1[4][64], smv2[4][64];
    __shared__ int   smi1[4][64];

    const int tid  = threadIdx.x;
    const int lane = tid & 63;
    const int w    = tid >> 6;
    const int tt   = blockIdx.x >> 1;
    const int h    = blockIdx.x & 1;
    const int n0   = tt * 64;

    // ---- stage z fp32 -> f16, swizzled, once (64 tokens x 256 C) ----
    float zsq = 0.0f;
    {
        const int cc = tid >> 3;            // chunk 0..31 = channels cc*8..+7
        #pragma unroll
        for (int hh = 0; hh < 2; ++hh) {
            const int q = (tid & 7) + hh * 8;   // token quad 0..15
            const float* zb = z + (n0 >> 10) * 262144 + (n0 & 1023) + q * 4;
            float4 f[8];
            #pragma unroll
            for (int j = 0; j < 8; ++j)
                f[j] = *reinterpret_cast<const float4*>(zb + (cc * 8 + j) * 1024);
            #pragma unroll
            for (int j = 0; j < 8; ++j)
                zsq += f[j].x * f[j].x + f[j].y * f[j].y + f[j].z * f[j].z + f[j].w * f[j].w;
            #pragma unroll
            for (int k = 0; k < 4; ++k) {
                const int t = q * 4 + k;
                half8 hv;
                #pragma unroll
                for (int j = 0; j < 8; ++j) {
                    const float v = k == 0 ? f[j].x : k == 1 ? f[j].y : k == 2 ? f[j].z : f[j].w;
                    hv[j] = (_Float16)v;
                }
                const int sw = (cc & 24) | ((cc & 7) ^ (t & 7));
                *reinterpret_cast<half8*>(&sB[t * 256 + sw * 8]) = hv;
            }
        }
    }
    if (h == 0) {
        #pragma unroll
        for (int off = 32; off > 0; off >>= 1) zsq += __shfl_down(zsq, off);
        if (lane == 0) atomicAdd(lsum, zsq);
    }

    const int nidx = lane & 15;   // token column
    const int g    = lane >> 4;   // k-quad / code sub-row

    __syncthreads();

    float m1[4] = {1e30f, 1e30f, 1e30f, 1e30f};
    float m2[4] = {1e30f, 1e30f, 1e30f, 1e30f};
    int   i1[4] = {0x7fffffff, 0x7fffffff, 0x7fffffff, 0x7fffffff};

    for (int ct = 0; ct < 4; ++ct) {
        const int cbase = h * 512 + w * 128 + ct * 32;
        const _Float16* arow = eh + (size_t)(cbase + nidx) * 256 + g * 8;

        f32x4 acc[2][4] = {};
        #pragma unroll
        for (int ks = 0; ks < 8; ++ks) {
            half8 a[2], b[4];
            #pragma unroll
            for (int mt = 0; mt < 2; ++mt)
                a[mt] = *reinterpret_cast<const half8*>(arow + mt * 4096 + ks * 32);
            const int cc = ks * 4 + g;
            #pragma unroll
            for (int nt = 0; nt < 4; ++nt) {
                const int row = nt * 16 + nidx;
                const int sw  = ((cc & 24) | ((cc & 7) ^ (row & 7))) * 8;
                b[nt] = *reinterpret_cast<const half8*>(&sB[row * 256 + sw]);
            }
            #pragma unroll
            for (int mt = 0; mt < 2; ++mt)
                #pragma unroll
                for (int nt = 0; nt < 4; ++nt)
                    acc[mt][nt] = __builtin_amdgcn_mfma_f32_16x16x32_f16(a[mt], b[nt], acc[mt][nt], 0, 0, 0);
        }
        // fold: lane's codes = cbase + mt*16 + g*4 + reg (ascending in mt,reg)
        #pragma unroll
        for (int mt = 0; mt < 2; ++mt) {
            const int c0 = cbase + mt * 16 + g * 4;
            const float4 en4 = *reinterpret_cast<const float4*>(enorm + c0);
            #pragma unroll
            for (int reg = 0; reg < 4; ++reg) {
                const float en = reg == 0 ? en4.x : reg == 1 ? en4.y : reg == 2 ? en4.z : en4.w;
                #pragma unroll
                for (int nt = 0; nt < 4; ++nt) {
                    const float d = fmaf(-2.0f, acc[mt][nt][reg], en);
                    if (d < m1[nt]) { m2[nt] = m1[nt]; m1[nt] = d; i1[nt] = c0 + reg; }
                    else            { m2[nt] = fminf(m2[nt], d); }
                }
            }
        }
    }

    // ---- merge the 4 g-lanes sharing each token column (xor 16, 32) ----
    #pragma unroll
    for (int nt = 0; nt < 4; ++nt) {
        float a1 = m1[nt], a2 = m2[nt]; int ai = i1[nt];
        #pragma unroll
        for (int off = 16; off < 64; off <<= 1) {
            const float o1 = __shfl_xor(a1, off);
            const int   oi = __shfl_xor(ai, off);
            const float o2 = __shfl_xor(a2, off);
            if (o1 < a1 || (o1 == a1 && oi < ai)) { a2 = fminf(a1, o2); a1 = o1; ai = oi; }
            else                                  { a2 = fminf(a2, o1); }
        }
        if (g == 0) {
            smv1[w][nt * 16 + nidx] = a1;
            smv2[w][nt * 16 + nidx] = a2;
            smi1[w][nt * 16 + nidx] = ai;
        }
    }
    __syncthreads();

    // ---- cross-wave merge (waves = ascending code blocks) -> partials ----
    if (tid < 64) {
        float b1 = smv1[0][tid], b2 = smv2[0][tid];
        int   bi = smi1[0][tid];
        #pragma unroll
        for (int ww = 1; ww < 4; ++ww) {
            const float c1 = smv1[ww][tid], c2 = smv2[ww][tid];
            const int   ci = smi1[ww][tid];
            if (c1 < b1 || (c1 == b1 && ci < bi)) { b2 = fminf(b1, c2); b1 = c1; bi = ci; }
            else                                  { b2 = fminf(b2, c1); }
        }
        const int o = h * 32768 + n0 + tid;
        pm1[o] = b1;
        pm2[o] = b2;
        pi [o] = bi;
    }
}

// ---------------------------------------------------------------------------
// Kernel 3: merge the 2 code-half partials -> final idx + rescue flags +
// sum of approx best-dists into lsum. Stashes merged m1 into pm1[n] so the
// rescue can apply an (exact - approx) correction. grid 128 x 256 threads.
// ---------------------------------------------------------------------------
__global__ __launch_bounds__(256) void vq_merge(
    float* __restrict__ pm1, const float* __restrict__ pm2,
    const int* __restrict__ pi, int* __restrict__ idx,
    int* __restrict__ nflag, int* __restrict__ flaglist,
    float* __restrict__ lsum)
{
    __shared__ float ssum[4];
    const int tid = threadIdx.x;
    const int n = blockIdx.x * 256 + tid;
    float b1 = pm1[n], b2 = pm2[n];
    int   bi = pi[n];
    const float c1 = pm1[32768 + n], c2 = pm2[32768 + n];
    const int   ci = pi[32768 + n];
    if (c1 < b1 || (c1 == b1 && ci < bi)) { b2 = fminf(b1, c2); b1 = c1; bi = ci; }
    else                                  { b2 = fminf(b2, c1); }
    idx[n] = bi;
    pm1[n] = b1;                       // stash merged approx best-dist
    if (b2 - b1 <= DELTA) {
        const int p = atomicAdd(nflag, 1);
        flaglist[p] = n;
    }
    // block-reduce sum of b1 -> lsum
    float s = b1;
    #pragma unroll
    for (int off = 32; off > 0; off >>= 1) s += __shfl_down(s, off);
    if ((tid & 63) == 0) ssum[tid >> 6] = s;
    __syncthreads();
    if (tid == 0) atomicAdd(lsum, ssum[0] + ssum[1] + ssum[2] + ssum[3]);
}

// ---------------------------------------------------------------------------
// Kernel 4: exact fp32 rescan, 8 tokens/block (codebook L2 reuse x8).
// grid 256 x 512 threads. Patches lsum with (exact - approx) per token.
// ---------------------------------------------------------------------------
__global__ __launch_bounds__(512) void vq_rescue(
    const float* __restrict__ z, const float* __restrict__ cb,
    const float* __restrict__ enorm, const int* __restrict__ nflag,
    const int* __restrict__ flaglist, int* __restrict__ idx,
    const float* __restrict__ pm1, float* __restrict__ lsum)
{
    __shared__ float zs[8][256];
    __shared__ float rv[8][512];
    __shared__ int   ri[8][512];
    const int tid = threadIdx.x;
    const int count = *nflag;
    for (int base = blockIdx.x * 8; base < count; base += 2048) {
        const int nt = min(8, count - base);
        __syncthreads();
        for (int t = tid >> 8; t < nt; t += 2) {
            const int n = flaglist[base + t];
            const int c = tid & 255;
            zs[t][c] = z[(n >> 10) * 262144 + c * 1024 + (n & 1023)];
        }
        __syncthreads();
        float bv[8] = {1e30f, 1e30f, 1e30f, 1e30f, 1e30f, 1e30f, 1e30f, 1e30f};
        int   bi[8] = {0x7fffffff, 0x7fffffff, 0x7fffffff, 0x7fffffff,
                       0x7fffffff, 0x7fffffff, 0x7fffffff, 0x7fffffff};
        #pragma unroll
        for (int j = 0; j < 2; ++j) {
            const int k = tid * 2 + j;
            const float* er = cb + k * 256;
            float s[8] = {0.f, 0.f, 0.f, 0.f, 0.f, 0.f, 0.f, 0.f};
            for (int c = 0; c < 256; c += 4) {
                const float4 e4 = *reinterpret_cast<const float4*>(er + c);
                #pragma unroll
                for (int t = 0; t < 8; ++t)
                    s[t] = fmaf(e4.x, zs[t][c], fmaf(e4.y, zs[t][c+1],
                           fmaf(e4.z, zs[t][c+2], fmaf(e4.w, zs[t][c+3], s[t]))));
            }
            const float en = enorm[k];
            #pragma unroll
            for (int t = 0; t < 8; ++t) {
                const float d = fmaf(-2.0f, s[t], en);
                if (d < bv[t]) { bv[t] = d; bi[t] = k; }
            }
        }
        #pragma unroll
        for (int t = 0; t < 8; ++t) { rv[t][tid] = bv[t]; ri[t][tid] = bi[t]; }
        __syncthreads();
        const int wv = tid >> 6, lane = tid & 63;
        if (wv < nt) {
            float m = rv[wv][lane]; int mi = ri[wv][lane];
            #pragma unroll
            for (int s2 = 1; s2 < 8; ++s2) {
                const float v = rv[wv][lane + s2 * 64]; const int ii = ri[wv][lane + s2 * 64];
                if (v < m || (v == m && ii < mi)) { m = v; mi = ii; }
            }
            #pragma unroll
            for (int off = 32; off > 0; off >>= 1) {
                const float ov = __shfl_down(m, off); const int oi = __shfl_down(mi, off);
                if (ov < m || (ov == m && oi < mi)) { m = ov; mi = oi; }
            }
            if (lane == 0) {
                const int n = flaglist[base + wv];
                idx[n] = mi;
                atomicAdd(lsum, m - pm1[n]);   // replace approx with exact
            }
        }
    }
}

// ---------------------------------------------------------------------------
// Kernel 5: gather z_q -> out + histogram ONLY (loss already in lsum).
// grid 2048: block = 64 tokens x 64 channels; histogram only from ctile 0.
// Write-bound: 128 MB out + L2-hot cb gathers.
// ---------------------------------------------------------------------------
__global__ __launch_bounds__(256) void vq_epilogue(
    const float* __restrict__ cb, const int* __restrict__ idx,
    float* __restrict__ out, int* __restrict__ counts)
{
    __shared__ int sidx[64];
    const int tid   = threadIdx.x;
    const int ntile = blockIdx.x >> 2;
    const int ctile = blockIdx.x & 3;
    const int n0    = ntile * 64;
    if (tid < 64) {
        const int ii = idx[n0 + tid];
        sidx[tid] = ii;
        if (ctile == 0) atomicAdd(&counts[ii], 1);
    }
    __syncthreads();
    float* ob = out + (n0 >> 10) * 262144 + (n0 & 1023);
    const int t   = tid & 63;
    const int cb0 = ctile * 64 + (tid >> 6) * 16;
    const int row = sidx[t] << 8;
    #pragma unroll
    for (int j = 0; j < 16; ++j) {
        const int c = cb0 + j;
        ob[c * 1024 + t] = cb[row + c];
    }
}

// ---------------------------------------------------------------------------
// Kernel 6: scalars.
// ---------------------------------------------------------------------------
__global__ __launch_bounds__(256) void vq_finalize(
    const int* __restrict__ counts, const float* __restrict__ lsum,
    float* __restrict__ outs)
{
    __shared__ float ssum[4];
    const int tid = threadIdx.x;
    float local = 0.0f;
    #pragma unroll
    for (int k = tid; k < 1024; k += 256) {
        float p = (float)counts[k] * (1.0f / 32768.0f);
        p = fmaxf(p, 1e-10f);
        local += p * logf(p);
    }
    #pragma unroll
    for (int off = 32; off > 0; off >>= 1) local += __shfl_down(local, off);
    if ((tid & 63) == 0) ssum[tid >> 6] = local;
    __syncthreads();
    if (tid == 0) {
        const float ent = ssum[0] + ssum[1] + ssum[2] + ssum[3];
        outs[0] = lsum[0] * ((1.0f + BETA) / 8388608.0f);
        outs[1] = expf(-ent);
    }
}

extern "C" void kernel_launch(void* const* d_in, const int* in_sizes, int n_in,
                              void* d_out, int out_size, void* d_ws, size_t ws_size,
                              hipStream_t stream)
{
    const float* z  = (const float*)d_in[0];
    const float* cb = (const float*)d_in[1];
    float* out = (float*)d_out;

    // d_out doubles as partial-result scratch (epilogue rewrites all of out)
    float* pm1 = (float*)d_out;            // [2][32768]; after merge [n]=merged
    float* pm2 = pm1 + 65536;              // [2][32768]
    int*   pi  = (int*)(pm1 + 131072);     // [2][32768]

    char* ws = (char*)d_ws;
    _Float16* eh     = (_Float16*)(ws);
    float*    enorm  = (float*)   (ws + 524288);
    int*      idx    = (int*)     (ws + 528384);
    int*      counts = (int*)     (ws + 659456);
    float*    lsum   = (float*)   (ws + 663552);
    int*      nflag  = (int*)     (ws + 663616);
    int*      flag   = (int*)     (ws + 663680);

    vq_prep_cb <<<256, 256, 0, stream>>>(cb, eh, enorm, counts, lsum, nflag);
    vq_mfma    <<<1024, 256, 0, stream>>>(z, eh, enorm, pm1, pm2, pi, lsum);
    vq_merge   <<<128, 256, 0, stream>>>(pm1, pm2, pi, idx, nflag, flag, lsum);
    vq_rescue  <<<256, 512, 0, stream>>>(z, cb, enorm, nflag, flag, idx, pm1, lsum);
    vq_epilogue<<<2048, 256, 0, stream>>>(cb, idx, out, counts);
    vq_finalize<<<1, 256, 0, stream>>>(counts, lsum, out + 8388608);
}

// Round 6
// 188.304 us; speedup vs baseline: 1.1422x; 1.1422x over previous
//
#include <hip/hip_runtime.h>

// VectorQuantizer on MI355X — round 12: loss algebra kept, contended atomics
// removed. r11's mfma regression (48->62us) attributed to the same-address
// atomicAdd(lsum) before __syncthreads: vmcnt(0) drain before s_barrier makes
// every h==0 wave wait for its serialized atomic (~2048 atomics to one line).
// Fix: all loss partial sums go to per-block slots via plain stores
// (zsqpart[512] from mfma h==0 blocks, msump[128] from merge, rescpart[256]
// from rescue); finalize sums them. Scan kernel is exactly r10's proven 48us
// structure plus a block-uniform-gated zsq computation. Rescue reverted to
// r10's 4-token shape. Epilogue stays write-only (no z read).
// z: [32,256,32,32] fp32; codebook: [1024,256] fp32; N=32768, K=1024, C=256.
// dist = |e|^2 - 2 z.e; (z_q-z)^2 summed = sum|z|^2 + sum(dist_chosen).
// Single-pass fp16 MFMA approx; tokens with approx top-2 gap <= DELTA=0.3
// get an exact fp32 rescan which also patches (exact - approx) into the sum.
//
// ws layout (bytes):
//   eh       @ 0        _Float16[1024*256]  (524288)
//   enorm    @ 524288   float[1024]
//   idx      @ 528384   int[32768]
//   counts   @ 659456   int[1024]
//   (gap)    @ 663552
//   nflag    @ 663616   int
//   flag     @ 663680   int[32768]      (ends 794752)
//   zsqpart  @ 794752   float[512]
//   msump    @ 796800   float[128]
//   rescpart @ 797312   float[256]      (ends 798336)
// d_out scratch (epilogue rewrites all of out):
//   pm1 @ float[0..65536)   per-half best dist [h][n]; after merge: [n]=merged
//   pm2 @ float[65536..)    per-half 2nd dist  [h][n]
//   pi  @ int  [131072..)   per-half best idx  [h][n]

#define BETA  0.25f
#define DELTA 0.3f

typedef _Float16 half8 __attribute__((ext_vector_type(8)));
typedef float    f32x4 __attribute__((ext_vector_type(4)));

// ---------------------------------------------------------------------------
// Kernel 1: codebook -> eh f16 + exact |e|^2 + init accumulators. grid 256.
// ---------------------------------------------------------------------------
__global__ __launch_bounds__(256) void vq_prep_cb(
    const float* __restrict__ cb, _Float16* __restrict__ eh,
    float* __restrict__ enorm, int* __restrict__ counts,
    int* __restrict__ nflag)
{
    const int tid = threadIdx.x;
    if (blockIdx.x < 4) counts[blockIdx.x * 256 + tid] = 0;
    if (blockIdx.x == 4 && tid == 0) *nflag = 0;

    const int lane = tid & 63;
    const int r    = blockIdx.x * 4 + (tid >> 6);
    const float4 v = *reinterpret_cast<const float4*>(cb + r * 256 + lane * 4);
    _Float16 h0 = (_Float16)v.x, h1 = (_Float16)v.y, h2 = (_Float16)v.z, h3 = (_Float16)v.w;
    *reinterpret_cast<ushort4*>(eh + r * 256 + lane * 4) =
        make_ushort4(*(unsigned short*)&h0, *(unsigned short*)&h1,
                     *(unsigned short*)&h2, *(unsigned short*)&h3);
    float s = v.x * v.x + v.y * v.y + v.z * v.z + v.w * v.w;
    #pragma unroll
    for (int off = 32; off > 0; off >>= 1) s += __shfl_down(s, off);
    if (lane == 0) enorm[r] = s;
}

// ---------------------------------------------------------------------------
// Kernel 2: fused MFMA distance scan, code-split (r10 structure, 48us).
// grid 1024 x 256 threads: blockIdx = token-tile*2 + half. 64 tokens staged
// fp32->f16 into the xor-swizzled LDS tile; h==0 blocks additionally compute
// exact fp32 sum|z|^2 for the tile and store it to zsqpart[tt] (plain store,
// no atomics -> no vmcnt stall at the barrier).
// Wave w scans codes [h*512 + w*128, +128) in 4 tiles of 32 (mt=2, nt=4).
// Output: per-half top-2 partials (pm1/pm2/pi), merged by vq_merge.
// ---------------------------------------------------------------------------
__global__ __launch_bounds__(256) void vq_mfma(
    const float* __restrict__ z, const _Float16* __restrict__ eh,
    const float* __restrict__ enorm,
    float* __restrict__ pm1, float* __restrict__ pm2, int* __restrict__ pi,
    float* __restrict__ zsqpart)
{
    __shared__ _Float16 sB[64 * 256];
    __shared__ float smv1[4][64], smv2[4][64];
    __shared__ int   smi1[4][64];
    __shared__ float szsq[4];

    const int tid  = threadIdx.x;
    const int lane = tid & 63;
    const int w    = tid >> 6;
    const int tt   = blockIdx.x >> 1;
    const int h    = blockIdx.x & 1;
    const int n0   = tt * 64;

    // ---- stage z fp32 -> f16, swizzled, once (64 tokens x 256 C) ----
    float zsq = 0.0f;
    {
        const int cc = tid >> 3;            // chunk 0..31 = channels cc*8..+7
        #pragma unroll
        for (int hh = 0; hh < 2; ++hh) {
            const int q = (tid & 7) + hh * 8;   // token quad 0..15
            const float* zb = z + (n0 >> 10) * 262144 + (n0 & 1023) + q * 4;
            float4 f[8];
            #pragma unroll
            for (int j = 0; j < 8; ++j)
                f[j] = *reinterpret_cast<const float4*>(zb + (cc * 8 + j) * 1024);
            if (h == 0) {     // block-uniform branch; h==1 path identical to r10
                #pragma unroll
                for (int j = 0; j < 8; ++j)
                    zsq += f[j].x * f[j].x + f[j].y * f[j].y + f[j].z * f[j].z + f[j].w * f[j].w;
            }
            #pragma unroll
            for (int k = 0; k < 4; ++k) {
                const int t = q * 4 + k;
                half8 hv;
                #pragma unroll
                for (int j = 0; j < 8; ++j) {
                    const float v = k == 0 ? f[j].x : k == 1 ? f[j].y : k == 2 ? f[j].z : f[j].w;
                    hv[j] = (_Float16)v;
                }
                const int sw = (cc & 24) | ((cc & 7) ^ (t & 7));
                *reinterpret_cast<half8*>(&sB[t * 256 + sw * 8]) = hv;
            }
        }
    }
    if (h == 0) {
        #pragma unroll
        for (int off = 32; off > 0; off >>= 1) zsq += __shfl_down(zsq, off);
        if (lane == 0) szsq[w] = zsq;
    }

    const int nidx = lane & 15;   // token column
    const int g    = lane >> 4;   // k-quad / code sub-row

    __syncthreads();

    float m1[4] = {1e30f, 1e30f, 1e30f, 1e30f};
    float m2[4] = {1e30f, 1e30f, 1e30f, 1e30f};
    int   i1[4] = {0x7fffffff, 0x7fffffff, 0x7fffffff, 0x7fffffff};

    for (int ct = 0; ct < 4; ++ct) {
        const int cbase = h * 512 + w * 128 + ct * 32;
        const _Float16* arow = eh + (size_t)(cbase + nidx) * 256 + g * 8;

        f32x4 acc[2][4] = {};
        #pragma unroll
        for (int ks = 0; ks < 8; ++ks) {
            half8 a[2], b[4];
            #pragma unroll
            for (int mt = 0; mt < 2; ++mt)
                a[mt] = *reinterpret_cast<const half8*>(arow + mt * 4096 + ks * 32);
            const int cc = ks * 4 + g;
            #pragma unroll
            for (int nt = 0; nt < 4; ++nt) {
                const int row = nt * 16 + nidx;
                const int sw  = ((cc & 24) | ((cc & 7) ^ (row & 7))) * 8;
                b[nt] = *reinterpret_cast<const half8*>(&sB[row * 256 + sw]);
            }
            #pragma unroll
            for (int mt = 0; mt < 2; ++mt)
                #pragma unroll
                for (int nt = 0; nt < 4; ++nt)
                    acc[mt][nt] = __builtin_amdgcn_mfma_f32_16x16x32_f16(a[mt], b[nt], acc[mt][nt], 0, 0, 0);
        }
        // fold: lane's codes = cbase + mt*16 + g*4 + reg (ascending in mt,reg)
        #pragma unroll
        for (int mt = 0; mt < 2; ++mt) {
            const int c0 = cbase + mt * 16 + g * 4;
            const float4 en4 = *reinterpret_cast<const float4*>(enorm + c0);
            #pragma unroll
            for (int reg = 0; reg < 4; ++reg) {
                const float en = reg == 0 ? en4.x : reg == 1 ? en4.y : reg == 2 ? en4.z : en4.w;
                #pragma unroll
                for (int nt = 0; nt < 4; ++nt) {
                    const float d = fmaf(-2.0f, acc[mt][nt][reg], en);
                    if (d < m1[nt]) { m2[nt] = m1[nt]; m1[nt] = d; i1[nt] = c0 + reg; }
                    else            { m2[nt] = fminf(m2[nt], d); }
                }
            }
        }
    }

    // ---- merge the 4 g-lanes sharing each token column (xor 16, 32) ----
    #pragma unroll
    for (int nt = 0; nt < 4; ++nt) {
        float a1 = m1[nt], a2 = m2[nt]; int ai = i1[nt];
        #pragma unroll
        for (int off = 16; off < 64; off <<= 1) {
            const float o1 = __shfl_xor(a1, off);
            const int   oi = __shfl_xor(ai, off);
            const float o2 = __shfl_xor(a2, off);
            if (o1 < a1 || (o1 == a1 && oi < ai)) { a2 = fminf(a1, o2); a1 = o1; ai = oi; }
            else                                  { a2 = fminf(a2, o1); }
        }
        if (g == 0) {
            smv1[w][nt * 16 + nidx] = a1;
            smv2[w][nt * 16 + nidx] = a2;
            smi1[w][nt * 16 + nidx] = ai;
        }
    }
    __syncthreads();

    // ---- cross-wave merge (waves = ascending code blocks) -> partials ----
    if (tid < 64) {
        float b1 = smv1[0][tid], b2 = smv2[0][tid];
        int   bi = smi1[0][tid];
        #pragma unroll
        for (int ww = 1; ww < 4; ++ww) {
            const float c1 = smv1[ww][tid], c2 = smv2[ww][tid];
            const int   ci = smi1[ww][tid];
            if (c1 < b1 || (c1 == b1 && ci < bi)) { b2 = fminf(b1, c2); b1 = c1; bi = ci; }
            else                                  { b2 = fminf(b2, c1); }
        }
        const int o = h * 32768 + n0 + tid;
        pm1[o] = b1;
        pm2[o] = b2;
        pi [o] = bi;
    }
    if (h == 0 && tid == 0)
        zsqpart[tt] = szsq[0] + szsq[1] + szsq[2] + szsq[3];
}

// ---------------------------------------------------------------------------
// Kernel 3: merge the 2 code-half partials -> final idx + rescue flags +
// per-block sum of approx best-dists into msump (plain store). Stashes merged
// m1 into pm1[n] for the rescue correction. grid 128 x 256 threads.
// ---------------------------------------------------------------------------
__global__ __launch_bounds__(256) void vq_merge(
    float* __restrict__ pm1, const float* __restrict__ pm2,
    const int* __restrict__ pi, int* __restrict__ idx,
    int* __restrict__ nflag, int* __restrict__ flaglist,
    float* __restrict__ msump)
{
    __shared__ float ssum[4];
    const int tid = threadIdx.x;
    const int n = blockIdx.x * 256 + tid;
    float b1 = pm1[n], b2 = pm2[n];
    int   bi = pi[n];
    const float c1 = pm1[32768 + n], c2 = pm2[32768 + n];
    const int   ci = pi[32768 + n];
    if (c1 < b1 || (c1 == b1 && ci < bi)) { b2 = fminf(b1, c2); b1 = c1; bi = ci; }
    else                                  { b2 = fminf(b2, c1); }
    idx[n] = bi;
    pm1[n] = b1;                       // stash merged approx best-dist
    if (b2 - b1 <= DELTA) {
        const int p = atomicAdd(nflag, 1);
        flaglist[p] = n;
    }
    float s = b1;
    #pragma unroll
    for (int off = 32; off > 0; off >>= 1) s += __shfl_down(s, off);
    if ((tid & 63) == 0) ssum[tid >> 6] = s;
    __syncthreads();
    if (tid == 0) msump[blockIdx.x] = ssum[0] + ssum[1] + ssum[2] + ssum[3];
}

// ---------------------------------------------------------------------------
// Kernel 4: exact fp32 rescan, 4 tokens/block (r10 proven shape).
// grid 256 x 512 threads. Accumulates (exact - approx) corrections locally,
// one plain store per block into rescpart.
// ---------------------------------------------------------------------------
__global__ __launch_bounds__(512) void vq_rescue(
    const float* __restrict__ z, const float* __restrict__ cb,
    const float* __restrict__ enorm, const int* __restrict__ nflag,
    const int* __restrict__ flaglist, int* __restrict__ idx,
    const float* __restrict__ pm1, float* __restrict__ rescpart)
{
    __shared__ float zs[4][256];
    __shared__ float rv[4][512];
    __shared__ int   ri[4][512];
    __shared__ float rsum[8];
    const int tid = threadIdx.x;
    const int count = *nflag;
    float rcorr = 0.0f;
    for (int base = blockIdx.x * 4; base < count; base += 1024) {
        const int nt = min(4, count - base);
        __syncthreads();
        for (int t = tid >> 8; t < nt; t += 2) {
            const int n = flaglist[base + t];
            const int c = tid & 255;
            zs[t][c] = z[(n >> 10) * 262144 + c * 1024 + (n & 1023)];
        }
        __syncthreads();
        float bv[4] = {1e30f, 1e30f, 1e30f, 1e30f};
        int   bi[4] = {0x7fffffff, 0x7fffffff, 0x7fffffff, 0x7fffffff};
        #pragma unroll
        for (int j = 0; j < 2; ++j) {
            const int k = tid * 2 + j;
            const float* er = cb + k * 256;
            float s0 = 0.f, s1 = 0.f, s2 = 0.f, s3 = 0.f;
            #pragma unroll 4
            for (int c = 0; c < 256; c += 4) {
                const float4 e4 = *reinterpret_cast<const float4*>(er + c);
                s0 = fmaf(e4.x, zs[0][c], fmaf(e4.y, zs[0][c+1], fmaf(e4.z, zs[0][c+2], fmaf(e4.w, zs[0][c+3], s0))));
                s1 = fmaf(e4.x, zs[1][c], fmaf(e4.y, zs[1][c+1], fmaf(e4.z, zs[1][c+2], fmaf(e4.w, zs[1][c+3], s1))));
                s2 = fmaf(e4.x, zs[2][c], fmaf(e4.y, zs[2][c+1], fmaf(e4.z, zs[2][c+2], fmaf(e4.w, zs[2][c+3], s2))));
                s3 = fmaf(e4.x, zs[3][c], fmaf(e4.y, zs[3][c+1], fmaf(e4.z, zs[3][c+2], fmaf(e4.w, zs[3][c+3], s3))));
            }
            const float en = enorm[k];
            float d;
            d = fmaf(-2.0f, s0, en); if (d < bv[0]) { bv[0] = d; bi[0] = k; }
            d = fmaf(-2.0f, s1, en); if (d < bv[1]) { bv[1] = d; bi[1] = k; }
            d = fmaf(-2.0f, s2, en); if (d < bv[2]) { bv[2] = d; bi[2] = k; }
            d = fmaf(-2.0f, s3, en); if (d < bv[3]) { bv[3] = d; bi[3] = k; }
        }
        #pragma unroll
        for (int t = 0; t < 4; ++t) { rv[t][tid] = bv[t]; ri[t][tid] = bi[t]; }
        __syncthreads();
        const int wv = tid >> 6, lane = tid & 63;
        if (wv < nt) {
            float m = rv[wv][lane]; int mi = ri[wv][lane];
            #pragma unroll
            for (int s2 = 1; s2 < 8; ++s2) {
                const float v = rv[wv][lane + s2 * 64]; const int ii = ri[wv][lane + s2 * 64];
                if (v < m || (v == m && ii < mi)) { m = v; mi = ii; }
            }
            #pragma unroll
            for (int off = 32; off > 0; off >>= 1) {
                const float ov = __shfl_down(m, off); const int oi = __shfl_down(mi, off);
                if (ov < m || (ov == m && oi < mi)) { m = ov; mi = oi; }
            }
            if (lane == 0) {
                const int n = flaglist[base + wv];
                idx[n] = mi;
                rcorr += m - pm1[n];           // local; no atomic
            }
        }
    }
    // block-reduce rcorr -> rescpart[bid] (plain store)
    __syncthreads();
    #pragma unroll
    for (int off = 32; off > 0; off >>= 1) rcorr += __shfl_down(rcorr, off);
    if ((tid & 63) == 0) rsum[tid >> 6] = rcorr;
    __syncthreads();
    if (tid == 0)
        rescpart[blockIdx.x] = rsum[0] + rsum[1] + rsum[2] + rsum[3]
                             + rsum[4] + rsum[5] + rsum[6] + rsum[7];
}

// ---------------------------------------------------------------------------
// Kernel 5: gather z_q -> out + histogram ONLY (loss via partial sums).
// grid 2048: block = 64 tokens x 64 channels; histogram only from ctile 0.
// ---------------------------------------------------------------------------
__global__ __launch_bounds__(256) void vq_epilogue(
    const float* __restrict__ cb, const int* __restrict__ idx,
    float* __restrict__ out, int* __restrict__ counts)
{
    __shared__ int sidx[64];
    const int tid   = threadIdx.x;
    const int ntile = blockIdx.x >> 2;
    const int ctile = blockIdx.x & 3;
    const int n0    = ntile * 64;
    if (tid < 64) {
        const int ii = idx[n0 + tid];
        sidx[tid] = ii;
        if (ctile == 0) atomicAdd(&counts[ii], 1);
    }
    __syncthreads();
    float* ob = out + (n0 >> 10) * 262144 + (n0 & 1023);
    const int t   = tid & 63;
    const int cb0 = ctile * 64 + (tid >> 6) * 16;
    const int row = sidx[t] << 8;
    #pragma unroll
    for (int j = 0; j < 16; ++j) {
        const int c = cb0 + j;
        ob[c * 1024 + t] = cb[row + c];
    }
}

// ---------------------------------------------------------------------------
// Kernel 6: scalars. Sums the loss partials (512+128+256 floats) + entropy.
// ---------------------------------------------------------------------------
__global__ __launch_bounds__(256) void vq_finalize(
    const int* __restrict__ counts, const float* __restrict__ zsqpart,
    const float* __restrict__ msump, const float* __restrict__ rescpart,
    float* __restrict__ outs)
{
    __shared__ float ssum[4];
    __shared__ float stot;
    const int tid = threadIdx.x;

    // ---- loss sum ----
    float local = zsqpart[tid] + zsqpart[tid + 256] + rescpart[tid];
    if (tid < 128) local += msump[tid];
    #pragma unroll
    for (int off = 32; off > 0; off >>= 1) local += __shfl_down(local, off);
    if ((tid & 63) == 0) ssum[tid >> 6] = local;
    __syncthreads();
    if (tid == 0) stot = ssum[0] + ssum[1] + ssum[2] + ssum[3];
    __syncthreads();

    // ---- entropy ----
    float ent = 0.0f;
    #pragma unroll
    for (int k = tid; k < 1024; k += 256) {
        float p = (float)counts[k] * (1.0f / 32768.0f);
        p = fmaxf(p, 1e-10f);
        ent += p * logf(p);
    }
    #pragma unroll
    for (int off = 32; off > 0; off >>= 1) ent += __shfl_down(ent, off);
    if ((tid & 63) == 0) ssum[tid >> 6] = ent;
    __syncthreads();
    if (tid == 0) {
        const float e = ssum[0] + ssum[1] + ssum[2] + ssum[3];
        outs[0] = stot * ((1.0f + BETA) / 8388608.0f);
        outs[1] = expf(-e);
    }
}

extern "C" void kernel_launch(void* const* d_in, const int* in_sizes, int n_in,
                              void* d_out, int out_size, void* d_ws, size_t ws_size,
                              hipStream_t stream)
{
    const float* z  = (const float*)d_in[0];
    const float* cb = (const float*)d_in[1];
    float* out = (float*)d_out;

    // d_out doubles as partial-result scratch (epilogue rewrites all of out)
    float* pm1 = (float*)d_out;            // [2][32768]; after merge [n]=merged
    float* pm2 = pm1 + 65536;              // [2][32768]
    int*   pi  = (int*)(pm1 + 131072);     // [2][32768]

    char* ws = (char*)d_ws;
    _Float16* eh       = (_Float16*)(ws);
    float*    enorm    = (float*)   (ws + 524288);
    int*      idx      = (int*)     (ws + 528384);
    int*      counts   = (int*)     (ws + 659456);
    int*      nflag    = (int*)     (ws + 663616);
    int*      flag     = (int*)     (ws + 663680);
    float*    zsqpart  = (float*)   (ws + 794752);
    float*    msump    = (float*)   (ws + 796800);
    float*    rescpart = (float*)   (ws + 797312);

    vq_prep_cb <<<256, 256, 0, stream>>>(cb, eh, enorm, counts, nflag);
    vq_mfma    <<<1024, 256, 0, stream>>>(z, eh, enorm, pm1, pm2, pi, zsqpart);
    vq_merge   <<<128, 256, 0, stream>>>(pm1, pm2, pi, idx, nflag, flag, msump);
    vq_rescue  <<<256, 512, 0, stream>>>(z, cb, enorm, nflag, flag, idx, pm1, rescpart);
    vq_epilogue<<<2048, 256, 0, stream>>>(cb, idx, out, counts);
    vq_finalize<<<1, 256, 0, stream>>>(counts, zsqpart, msump, rescpart, out + 8388608);
}